// Round 1
// baseline (555.566 us; speedup 1.0000x reference)
//
#include <hip/hip_runtime.h>
#include <hip/hip_bf16.h>

#define NN 50000
#define EE 800000
#define ETOT (EE + NN)
#define F 128
#define HEADS 4
#define MT 64

// ---------------- CSR build ----------------

__global__ void count_k(const int* __restrict__ ei, int* __restrict__ counts) {
    int e = blockIdx.x * blockDim.x + threadIdx.x;
    if (e >= ETOT) return;
    int dst = (e < EE) ? ei[EE + e] : (e - EE);
    atomicAdd(&counts[dst], 1);
}

__launch_bounds__(1024)
__global__ void scan_k(const int* __restrict__ counts, int* __restrict__ row_ptr, int n) {
    __shared__ int sm[1024];
    __shared__ int carry_s;
    int tid = threadIdx.x;
    if (tid == 0) carry_s = 0;
    __syncthreads();
    for (int base = 0; base < n; base += 1024) {
        int i = base + tid;
        int v = (i < n) ? counts[i] : 0;
        sm[tid] = v;
        __syncthreads();
        for (int off = 1; off < 1024; off <<= 1) {
            int t = (tid >= off) ? sm[tid - off] : 0;
            __syncthreads();
            sm[tid] += t;
            __syncthreads();
        }
        int carry = carry_s;
        if (i < n) row_ptr[i] = carry + sm[tid] - v;   // exclusive
        __syncthreads();
        if (tid == 1023) carry_s = carry + sm[1023];
        __syncthreads();
    }
    if (tid == 0) row_ptr[n] = carry_s;
}

__global__ void fill_k(const int* __restrict__ ei, const int* __restrict__ row_ptr,
                       int* __restrict__ cursor, int* __restrict__ csr_src) {
    int e = blockIdx.x * blockDim.x + threadIdx.x;
    if (e >= ETOT) return;
    int src, dst;
    if (e < EE) { src = ei[e]; dst = ei[EE + e]; }
    else        { src = e - EE; dst = e - EE; }
    int pos = row_ptr[dst] + atomicAdd(&cursor[dst], 1);
    csr_src[pos] = src;
}

// ---------------- GEMM: C[M,128] = A[M,128] @ W[128,128] ----------------
// block: 256 threads, tile 64 rows x 128 cols, x-tile in LDS, 8x4 reg acc.

__launch_bounds__(256)
__global__ void gemm128(const float* __restrict__ A, const float* __restrict__ W,
                        float* __restrict__ C, int M) {
    __shared__ float xs[MT][F];            // 32 KB
    int tid = threadIdx.x;
    int row0 = blockIdx.x * MT;

    for (int i = tid; i < MT * F / 4; i += 256) {
        int r  = i / (F / 4);
        int c4 = i % (F / 4);
        int gr = row0 + r;
        float4 v = (gr < M) ? ((const float4*)A)[(size_t)gr * (F / 4) + c4]
                            : make_float4(0.f, 0.f, 0.f, 0.f);
        ((float4*)&xs[r][0])[c4] = v;
    }
    __syncthreads();

    int cg = (tid & 31) * 4;      // output col
    int rg = (tid >> 5) * 8;      // output row start (within tile)
    float acc[8][4];
#pragma unroll
    for (int r = 0; r < 8; r++)
#pragma unroll
        for (int j = 0; j < 4; j++) acc[r][j] = 0.f;

    for (int k = 0; k < F; k += 4) {
        float4 w0 = *(const float4*)&W[(k + 0) * F + cg];
        float4 w1 = *(const float4*)&W[(k + 1) * F + cg];
        float4 w2 = *(const float4*)&W[(k + 2) * F + cg];
        float4 w3 = *(const float4*)&W[(k + 3) * F + cg];
#pragma unroll
        for (int r = 0; r < 8; r++) {
            float4 xv = *(const float4*)&xs[rg + r][k];
            acc[r][0] += xv.x * w0.x + xv.y * w1.x + xv.z * w2.x + xv.w * w3.x;
            acc[r][1] += xv.x * w0.y + xv.y * w1.y + xv.z * w2.y + xv.w * w3.y;
            acc[r][2] += xv.x * w0.z + xv.y * w1.z + xv.z * w2.z + xv.w * w3.z;
            acc[r][3] += xv.x * w0.w + xv.y * w1.w + xv.z * w2.w + xv.w * w3.w;
        }
    }

#pragma unroll
    for (int r = 0; r < 8; r++) {
        int gr = row0 + rg + r;
        if (gr < M)
            *(float4*)&C[(size_t)gr * F + cg] =
                make_float4(acc[r][0], acc[r][1], acc[r][2], acc[r][3]);
    }
}

// ---------------- per-node attention logits ----------------

__global__ void al_k(const float* __restrict__ h, const float* __restrict__ a_src,
                     const float* __restrict__ a_dst,
                     float* __restrict__ als, float* __restrict__ ald) {
    int idx = blockIdx.x * blockDim.x + threadIdx.x;   // n*4 + head
    if (idx >= NN * HEADS) return;
    int n = idx >> 2, hh = idx & 3;
    const float4* hp  = (const float4*)&h[(size_t)n * F + hh * 32];
    const float4* asp = (const float4*)&a_src[hh * 32];
    const float4* adp = (const float4*)&a_dst[hh * 32];
    float s = 0.f, d = 0.f;
#pragma unroll
    for (int i = 0; i < 8; i++) {
        float4 hv = hp[i], av = asp[i], dv = adp[i];
        s += hv.x * av.x + hv.y * av.y + hv.z * av.z + hv.w * av.w;
        d += hv.x * dv.x + hv.y * dv.y + hv.z * dv.z + hv.w * dv.w;
    }
    als[idx] = s;
    ald[idx] = d;
}

// ---------------- fused softmax + aggregate (gather, no atomics) ----------------
// one block (128 threads) per destination node; thread c owns channel c.

__launch_bounds__(128)
__global__ void aggregate(const float* __restrict__ h, const float* __restrict__ als,
                          const float* __restrict__ ald, const int* __restrict__ row_ptr,
                          const int* __restrict__ csr_src, const float* __restrict__ bias,
                          float* __restrict__ out, int apply_elu) {
    int n  = blockIdx.x;
    int c  = threadIdx.x;          // 0..127
    int hh = c >> 5;
    float aldv = ald[n * HEADS + hh];
    int jb = row_ptr[n], je = row_ptr[n + 1];
    float den = 0.f, acc = 0.f;
    for (int j = jb; j < je; j++) {
        int s = csr_src[j];
        float e = als[s * HEADS + hh] + aldv;
        e = (e > 0.f) ? e : 0.2f * e;          // leaky_relu
        float p = __expf(e);                    // no max-shift needed (|e| small)
        den += p;
        acc += p * h[(size_t)s * F + c];
    }
    float v = acc / den + bias[c];
    if (apply_elu) v = (v > 0.f) ? v : (__expf(v) - 1.f);
    out[(size_t)n * F + c] = v;
}

// ---------------- launch ----------------

extern "C" void kernel_launch(void* const* d_in, const int* in_sizes, int n_in,
                              void* d_out, int out_size, void* d_ws, size_t ws_size,
                              hipStream_t stream) {
    const float* x   = (const float*)d_in[0];
    const int*   ei  = (const int*)d_in[1];
    const float* W1  = (const float*)d_in[2];
    const float* as1 = (const float*)d_in[3];
    const float* ad1 = (const float*)d_in[4];
    const float* b1  = (const float*)d_in[5];
    const float* W2  = (const float*)d_in[6];
    const float* as2 = (const float*)d_in[7];
    const float* ad2 = (const float*)d_in[8];
    const float* b2  = (const float*)d_in[9];
    float* out = (float*)d_out;

    char* ws = (char*)d_ws;
    size_t off = 0;
    auto alloc = [&](size_t bytes) {
        void* p = ws + off;
        off += (bytes + 255) & ~(size_t)255;
        return p;
    };
    float* h       = (float*)alloc((size_t)NN * F * 4);   // 25.6 MB
    float* als     = (float*)alloc((size_t)NN * HEADS * 4);
    float* ald     = (float*)alloc((size_t)NN * HEADS * 4);
    int*   counts  = (int*)alloc((size_t)NN * 4);
    int*   cursor  = (int*)alloc((size_t)NN * 4);
    int*   row_ptr = (int*)alloc((size_t)(NN + 1) * 4);
    int*   csr_src = (int*)alloc((size_t)ETOT * 4);       // 3.4 MB

    // CSR build (identical for both layers)
    hipMemsetAsync(counts, 0, (size_t)NN * 4, stream);
    hipMemsetAsync(cursor, 0, (size_t)NN * 4, stream);
    count_k<<<(ETOT + 255) / 256, 256, 0, stream>>>(ei, counts);
    scan_k<<<1, 1024, 0, stream>>>(counts, row_ptr, NN);
    fill_k<<<(ETOT + 255) / 256, 256, 0, stream>>>(ei, row_ptr, cursor, csr_src);

    int gemm_grid = (NN + MT - 1) / MT;

    // ---- layer 1 ----  (layer-1 output lives in d_out, ELU applied)
    gemm128<<<gemm_grid, 256, 0, stream>>>(x, W1, h, NN);
    al_k<<<(NN * HEADS + 255) / 256, 256, 0, stream>>>(h, as1, ad1, als, ald);
    aggregate<<<NN, 128, 0, stream>>>(h, als, ald, row_ptr, csr_src, b1, out, 1);

    // ---- layer 2 ----
    gemm128<<<gemm_grid, 256, 0, stream>>>(out, W2, h, NN);
    al_k<<<(NN * HEADS + 255) / 256, 256, 0, stream>>>(h, as2, ad2, als, ald);
    aggregate<<<NN, 128, 0, stream>>>(h, als, ald, row_ptr, csr_src, b2, out, 0);
}

// Round 2
// 398.975 us; speedup vs baseline: 1.3925x; 1.3925x over previous
//
#include <hip/hip_runtime.h>
#include <hip/hip_bf16.h>

#define NN 50000
#define EE 800000
#define ETOT (EE + NN)
#define F 128
#define HEADS 4
#define MT 64
#define NB ((NN + 1023) / 1024)   // 49 scan chunks

// ---------------- CSR build ----------------

__global__ void count_k(const int* __restrict__ ei, int* __restrict__ counts) {
    int e = blockIdx.x * blockDim.x + threadIdx.x;
    if (e >= ETOT) return;
    int dst = (e < EE) ? ei[EE + e] : (e - EE);
    atomicAdd(&counts[dst], 1);
}

// per-1024-chunk exclusive scan (block-local), block totals to bsum
__launch_bounds__(1024)
__global__ void scan_block_k(const int* __restrict__ counts, int* __restrict__ row_ptr,
                             int* __restrict__ bsum, int n) {
    int tid = threadIdx.x;
    int i = blockIdx.x * 1024 + tid;
    int v = (i < n) ? counts[i] : 0;
    int lane = tid & 63;
    int wave = tid >> 6;               // 0..15
    int x = v;
#pragma unroll
    for (int off = 1; off < 64; off <<= 1) {
        int t = __shfl_up(x, off, 64);
        if (lane >= off) x += t;
    }
    __shared__ int wsum[16];
    if (lane == 63) wsum[wave] = x;
    __syncthreads();
    if (wave == 0) {
        int w = (lane < 16) ? wsum[lane] : 0;
#pragma unroll
        for (int off = 1; off < 16; off <<= 1) {
            int t = __shfl_up(w, off, 64);
            if (lane >= off) w += t;
        }
        if (lane < 16) wsum[lane] = w;
    }
    __syncthreads();
    int base = (wave > 0) ? wsum[wave - 1] : 0;
    int incl = base + x;
    if (i < n) row_ptr[i] = incl - v;          // exclusive within chunk
    if (tid == 1023) bsum[blockIdx.x] = incl;  // chunk total
}

// scan the 49 chunk totals in one wave (in-place -> exclusive offsets)
__global__ void scan_bsum_k(int* __restrict__ bsum, int nb) {
    int lane = threadIdx.x;
    int v = (lane < nb) ? bsum[lane] : 0;
    int x = v;
#pragma unroll
    for (int off = 1; off < 64; off <<= 1) {
        int t = __shfl_up(x, off, 64);
        if (lane >= off) x += t;
    }
    if (lane < nb) bsum[lane] = x - v;
}

__global__ void add_off_k(int* __restrict__ row_ptr, const int* __restrict__ bsum, int n) {
    int i = blockIdx.x * blockDim.x + threadIdx.x;
    if (i < n) row_ptr[i] += bsum[i >> 10];
    if (i == 0) row_ptr[n] = ETOT;
}

__global__ void fill_k(const int* __restrict__ ei, const int* __restrict__ row_ptr,
                       int* __restrict__ cursor, int* __restrict__ csr_src) {
    int e = blockIdx.x * blockDim.x + threadIdx.x;
    if (e >= ETOT) return;
    int src, dst;
    if (e < EE) { src = ei[e]; dst = ei[EE + e]; }
    else        { src = e - EE; dst = e - EE; }
    int pos = row_ptr[dst] + atomicAdd(&cursor[dst], 1);
    csr_src[pos] = src;
}

// ---------------- GEMM (64x128 tile) + fused attention-logit epilogue ----------------

__launch_bounds__(256)
__global__ void gemm128_al(const float* __restrict__ A, const float* __restrict__ W,
                           const float* __restrict__ a_src, const float* __restrict__ a_dst,
                           float* __restrict__ C, float* __restrict__ als,
                           float* __restrict__ ald, int M) {
    __shared__ float xs[MT][F];            // 32 KB
    int tid = threadIdx.x;
    int row0 = blockIdx.x * MT;

    for (int i = tid; i < MT * F / 4; i += 256) {
        int r  = i >> 5;
        int c4 = i & 31;
        int gr = row0 + r;
        float4 v = (gr < M) ? ((const float4*)A)[(size_t)gr * 32 + c4]
                            : make_float4(0.f, 0.f, 0.f, 0.f);
        ((float4*)&xs[r][0])[c4] = v;
    }
    __syncthreads();

    int cg = (tid & 31) * 4;      // output col
    int rg = (tid >> 5) * 8;      // output row start within tile
    float acc[8][4];
#pragma unroll
    for (int r = 0; r < 8; r++)
#pragma unroll
        for (int j = 0; j < 4; j++) acc[r][j] = 0.f;

    for (int k = 0; k < F; k += 4) {
        float4 w0 = *(const float4*)&W[(k + 0) * F + cg];
        float4 w1 = *(const float4*)&W[(k + 1) * F + cg];
        float4 w2 = *(const float4*)&W[(k + 2) * F + cg];
        float4 w3 = *(const float4*)&W[(k + 3) * F + cg];
#pragma unroll
        for (int r = 0; r < 8; r++) {
            float4 xv = *(const float4*)&xs[rg + r][k];
            acc[r][0] += xv.x * w0.x + xv.y * w1.x + xv.z * w2.x + xv.w * w3.x;
            acc[r][1] += xv.x * w0.y + xv.y * w1.y + xv.z * w2.y + xv.w * w3.y;
            acc[r][2] += xv.x * w0.z + xv.y * w1.z + xv.z * w2.z + xv.w * w3.z;
            acc[r][3] += xv.x * w0.w + xv.y * w1.w + xv.z * w2.w + xv.w * w3.w;
        }
    }

    // epilogue: store C rows + per-(row,head) logits via 8-lane shfl reduce
    int lane = tid & 63;
    int head = (tid & 31) >> 3;            // cg's head
    float4 asv = *(const float4*)&a_src[head * 32 + (lane & 7) * 4];
    float4 adv = *(const float4*)&a_dst[head * 32 + (lane & 7) * 4];
#pragma unroll
    for (int r = 0; r < 8; r++) {
        int gr = row0 + rg + r;
        if (gr < M)
            *(float4*)&C[(size_t)gr * F + cg] =
                make_float4(acc[r][0], acc[r][1], acc[r][2], acc[r][3]);
        float ps = acc[r][0] * asv.x + acc[r][1] * asv.y + acc[r][2] * asv.z + acc[r][3] * asv.w;
        float pd = acc[r][0] * adv.x + acc[r][1] * adv.y + acc[r][2] * adv.z + acc[r][3] * adv.w;
        ps += __shfl_xor(ps, 1); ps += __shfl_xor(ps, 2); ps += __shfl_xor(ps, 4);
        pd += __shfl_xor(pd, 1); pd += __shfl_xor(pd, 2); pd += __shfl_xor(pd, 4);
        if ((lane & 7) == 0 && gr < M) {
            als[gr * HEADS + head] = ps;
            ald[gr * HEADS + head] = pd;
        }
    }
}

// ---------------- fused softmax + aggregate: 8 edge-slots x 32 lanes ----------------

__launch_bounds__(256)
__global__ void aggregate(const float* __restrict__ h, const float* __restrict__ als,
                          const float* __restrict__ ald, const int* __restrict__ row_ptr,
                          const int* __restrict__ csr_src, const float* __restrict__ bias,
                          float* __restrict__ out, int apply_elu) {
    int n = blockIdx.x;
    int tid = threadIdx.x;
    int lane = tid & 31;          // float4 index: channels 4*lane..4*lane+3
    int slot = tid >> 5;          // 0..7 edge slots
    int head = lane >> 3;
    float aldv = ald[n * HEADS + head];
    int jb = row_ptr[n], je = row_ptr[n + 1];

    float4 acc = make_float4(0.f, 0.f, 0.f, 0.f);
    float den = 0.f;
    for (int j = jb + slot; j < je; j += 8) {
        int s = csr_src[j];
        float e = als[s * HEADS + head] + aldv;
        e = (e > 0.f) ? e : 0.2f * e;          // leaky_relu
        float p = __expf(e);                    // |e| small: no max-shift needed
        den += p;
        float4 hv = *(const float4*)&h[(size_t)s * F + lane * 4];
        acc.x += p * hv.x; acc.y += p * hv.y; acc.z += p * hv.z; acc.w += p * hv.w;
    }

    __shared__ float4 accs[8][32];
    __shared__ float  dens[8][4];
    accs[slot][lane] = acc;
    if ((lane & 7) == 0) dens[slot][head] = den;
    __syncthreads();

    if (slot == 0) {
        float4 a = accs[0][lane];
        float  d = dens[0][head];
#pragma unroll
        for (int t = 1; t < 8; t++) {
            float4 b = accs[t][lane];
            a.x += b.x; a.y += b.y; a.z += b.z; a.w += b.w;
            d += dens[t][head];
        }
        float inv = 1.f / d;
        float4 bv = *(const float4*)&bias[lane * 4];
        float4 v;
        v.x = a.x * inv + bv.x;
        v.y = a.y * inv + bv.y;
        v.z = a.z * inv + bv.z;
        v.w = a.w * inv + bv.w;
        if (apply_elu) {
            v.x = (v.x > 0.f) ? v.x : (__expf(v.x) - 1.f);
            v.y = (v.y > 0.f) ? v.y : (__expf(v.y) - 1.f);
            v.z = (v.z > 0.f) ? v.z : (__expf(v.z) - 1.f);
            v.w = (v.w > 0.f) ? v.w : (__expf(v.w) - 1.f);
        }
        *(float4*)&out[(size_t)n * F + lane * 4] = v;
    }
}

// ---------------- launch ----------------

extern "C" void kernel_launch(void* const* d_in, const int* in_sizes, int n_in,
                              void* d_out, int out_size, void* d_ws, size_t ws_size,
                              hipStream_t stream) {
    const float* x   = (const float*)d_in[0];
    const int*   ei  = (const int*)d_in[1];
    const float* W1  = (const float*)d_in[2];
    const float* as1 = (const float*)d_in[3];
    const float* ad1 = (const float*)d_in[4];
    const float* b1  = (const float*)d_in[5];
    const float* W2  = (const float*)d_in[6];
    const float* as2 = (const float*)d_in[7];
    const float* ad2 = (const float*)d_in[8];
    const float* b2  = (const float*)d_in[9];
    float* out = (float*)d_out;

    char* ws = (char*)d_ws;
    size_t off = 0;
    auto alloc = [&](size_t bytes) {
        void* p = ws + off;
        off += (bytes + 255) & ~(size_t)255;
        return p;
    };
    float* h       = (float*)alloc((size_t)NN * F * 4);   // 25.6 MB
    float* als     = (float*)alloc((size_t)NN * HEADS * 4);
    float* ald     = (float*)alloc((size_t)NN * HEADS * 4);
    int*   counts  = (int*)alloc((size_t)NN * 4);
    int*   cursor  = (int*)alloc((size_t)NN * 4);
    int*   row_ptr = (int*)alloc((size_t)(NN + 1) * 4);
    int*   bsum    = (int*)alloc((size_t)NB * 4);
    int*   csr_src = (int*)alloc((size_t)ETOT * 4);       // 3.4 MB

    // CSR build (shared by both layers)
    hipMemsetAsync(counts, 0, (size_t)NN * 4, stream);
    hipMemsetAsync(cursor, 0, (size_t)NN * 4, stream);
    count_k<<<(ETOT + 255) / 256, 256, 0, stream>>>(ei, counts);
    scan_block_k<<<NB, 1024, 0, stream>>>(counts, row_ptr, bsum, NN);
    scan_bsum_k<<<1, 64, 0, stream>>>(bsum, NB);
    add_off_k<<<(NN + 255) / 256, 256, 0, stream>>>(row_ptr, bsum, NN);
    fill_k<<<(ETOT + 255) / 256, 256, 0, stream>>>(ei, row_ptr, cursor, csr_src);

    int gemm_grid = (NN + MT - 1) / MT;

    // ---- layer 1 ----
    gemm128_al<<<gemm_grid, 256, 0, stream>>>(x, W1, as1, ad1, h, als, ald, NN);
    aggregate<<<NN, 256, 0, stream>>>(h, als, ald, row_ptr, csr_src, b1, out, 1);

    // ---- layer 2 ----
    gemm128_al<<<gemm_grid, 256, 0, stream>>>(out, W2, as2, ad2, h, als, ald, NN);
    aggregate<<<NN, 256, 0, stream>>>(h, als, ald, row_ptr, csr_src, b2, out, 0);
}

// Round 5
// 345.862 us; speedup vs baseline: 1.6063x; 1.1536x over previous
//
#include <hip/hip_runtime.h>
#include <hip/hip_bf16.h>

#define NN 50000
#define EE 800000
#define ETOT (EE + NN)
#define F 128
#define HEADS 4
#define MT 64
#define NB ((NN + 1023) / 1024)   // 49 scan chunks

// f32 -> bf16 bits, round-to-nearest-even (no dependency on __hip_bfloat16 layout)
__device__ __forceinline__ unsigned short f32_to_bf16(float f) {
    unsigned int u = __float_as_uint(f);
    u += 0x7fffu + ((u >> 16) & 1u);
    return (unsigned short)(u >> 16);
}

// ---------------- CSR build ----------------

__global__ void count_k(const int* __restrict__ ei, int* __restrict__ counts) {
    int e = blockIdx.x * blockDim.x + threadIdx.x;
    if (e >= ETOT) return;
    int dst = (e < EE) ? ei[EE + e] : (e - EE);
    atomicAdd(&counts[dst], 1);
}

__launch_bounds__(1024)
__global__ void scan_block_k(const int* __restrict__ counts, int* __restrict__ row_ptr,
                             int* __restrict__ bsum, int n) {
    int tid = threadIdx.x;
    int i = blockIdx.x * 1024 + tid;
    int v = (i < n) ? counts[i] : 0;
    int lane = tid & 63;
    int wave = tid >> 6;               // 0..15
    int x = v;
#pragma unroll
    for (int off = 1; off < 64; off <<= 1) {
        int t = __shfl_up(x, off, 64);
        if (lane >= off) x += t;
    }
    __shared__ int wsum[16];
    if (lane == 63) wsum[wave] = x;
    __syncthreads();
    if (wave == 0) {
        int w = (lane < 16) ? wsum[lane] : 0;
#pragma unroll
        for (int off = 1; off < 16; off <<= 1) {
            int t = __shfl_up(w, off, 64);
            if (lane >= off) w += t;
        }
        if (lane < 16) wsum[lane] = w;
    }
    __syncthreads();
    int base = (wave > 0) ? wsum[wave - 1] : 0;
    int incl = base + x;
    if (i < n) row_ptr[i] = incl - v;          // exclusive within chunk
    if (tid == 1023) bsum[blockIdx.x] = incl;  // chunk total
}

__global__ void scan_bsum_k(int* __restrict__ bsum, int nb) {
    int lane = threadIdx.x;
    int v = (lane < nb) ? bsum[lane] : 0;
    int x = v;
#pragma unroll
    for (int off = 1; off < 64; off <<= 1) {
        int t = __shfl_up(x, off, 64);
        if (lane >= off) x += t;
    }
    if (lane < nb) bsum[lane] = x - v;
}

__global__ void add_off_k(int* __restrict__ row_ptr, const int* __restrict__ bsum, int n) {
    int i = blockIdx.x * blockDim.x + threadIdx.x;
    if (i < n) row_ptr[i] += bsum[i >> 10];
    if (i == 0) row_ptr[n] = ETOT;
}

__global__ void fill_k(const int* __restrict__ ei, const int* __restrict__ row_ptr,
                       int* __restrict__ cursor, int* __restrict__ csr_src) {
    int e = blockIdx.x * blockDim.x + threadIdx.x;
    if (e >= ETOT) return;
    int src, dst;
    if (e < EE) { src = ei[e]; dst = ei[EE + e]; }
    else        { src = e - EE; dst = e - EE; }
    int pos = row_ptr[dst] + atomicAdd(&cursor[dst], 1);
    csr_src[pos] = src;
}

// ---------------- GEMM (64x128 tile) + logits epilogue, bf16 h output ----------------

__launch_bounds__(256)
__global__ void gemm128_al(const float* __restrict__ A, const float* __restrict__ W,
                           const float* __restrict__ a_src, const float* __restrict__ a_dst,
                           unsigned short* __restrict__ Cb, float* __restrict__ als,
                           float* __restrict__ ald, int M) {
    __shared__ float xs[MT][F];            // 32 KB
    int tid = threadIdx.x;
    int row0 = blockIdx.x * MT;

    for (int i = tid; i < MT * F / 4; i += 256) {
        int r  = i >> 5;
        int c4 = i & 31;
        int gr = row0 + r;
        float4 v = (gr < M) ? ((const float4*)A)[(size_t)gr * 32 + c4]
                            : make_float4(0.f, 0.f, 0.f, 0.f);
        ((float4*)&xs[r][0])[c4] = v;
    }
    __syncthreads();

    int cg = (tid & 31) * 4;      // output col
    int rg = (tid >> 5) * 8;      // output row start within tile
    float acc[8][4];
#pragma unroll
    for (int r = 0; r < 8; r++)
#pragma unroll
        for (int j = 0; j < 4; j++) acc[r][j] = 0.f;

    for (int k = 0; k < F; k += 4) {
        float4 w0 = *(const float4*)&W[(k + 0) * F + cg];
        float4 w1 = *(const float4*)&W[(k + 1) * F + cg];
        float4 w2 = *(const float4*)&W[(k + 2) * F + cg];
        float4 w3 = *(const float4*)&W[(k + 3) * F + cg];
#pragma unroll
        for (int r = 0; r < 8; r++) {
            float4 xv = *(const float4*)&xs[rg + r][k];
            acc[r][0] += xv.x * w0.x + xv.y * w1.x + xv.z * w2.x + xv.w * w3.x;
            acc[r][1] += xv.x * w0.y + xv.y * w1.y + xv.z * w2.y + xv.w * w3.y;
            acc[r][2] += xv.x * w0.z + xv.y * w1.z + xv.z * w2.z + xv.w * w3.z;
            acc[r][3] += xv.x * w0.w + xv.y * w1.w + xv.z * w2.w + xv.w * w3.w;
        }
    }

    int lane = tid & 63;
    int head = (tid & 31) >> 3;
    float4 asv = *(const float4*)&a_src[head * 32 + (lane & 7) * 4];
    float4 adv = *(const float4*)&a_dst[head * 32 + (lane & 7) * 4];
#pragma unroll
    for (int r = 0; r < 8; r++) {
        int gr = row0 + rg + r;
        if (gr < M) {
            ushort4 bv;
            bv.x = f32_to_bf16(acc[r][0]);
            bv.y = f32_to_bf16(acc[r][1]);
            bv.z = f32_to_bf16(acc[r][2]);
            bv.w = f32_to_bf16(acc[r][3]);
            *(ushort4*)&Cb[(size_t)gr * F + cg] = bv;
        }
        float ps = acc[r][0] * asv.x + acc[r][1] * asv.y + acc[r][2] * asv.z + acc[r][3] * asv.w;
        float pd = acc[r][0] * adv.x + acc[r][1] * adv.y + acc[r][2] * adv.z + acc[r][3] * adv.w;
        ps += __shfl_xor(ps, 1); ps += __shfl_xor(ps, 2); ps += __shfl_xor(ps, 4);
        pd += __shfl_xor(pd, 1); pd += __shfl_xor(pd, 2); pd += __shfl_xor(pd, 4);
        if ((lane & 7) == 0 && gr < M) {
            als[gr * HEADS + head] = ps;
            ald[gr * HEADS + head] = pd;
        }
    }
}

// ---------------- softmax + aggregate: wave per node, 4 edge-groups x 16 lanes ----------------

__launch_bounds__(256)
__global__ void aggregate(const unsigned short* __restrict__ hb, const float* __restrict__ als,
                          const float* __restrict__ ald, const int* __restrict__ row_ptr,
                          const int* __restrict__ csr_src, const float* __restrict__ bias,
                          float* __restrict__ out, int apply_elu) {
    int wave = threadIdx.x >> 6;
    int n = blockIdx.x * 4 + wave;
    if (n >= NN) return;
    int lane = threadIdx.x & 63;
    int g  = lane >> 4;           // edge group 0..3
    int cl = lane & 15;           // channels cl*8 .. cl*8+7
    int head = cl >> 2;
    float aldv = ald[n * HEADS + head];
    int jb = row_ptr[n], je = row_ptr[n + 1];

    float acc[8];
#pragma unroll
    for (int i = 0; i < 8; i++) acc[i] = 0.f;
    float den = 0.f;

    for (int j = jb + g; j < je; j += 4) {
        int s = csr_src[j];
        float e = als[s * HEADS + head] + aldv;
        e = (e > 0.f) ? e : 0.2f * e;          // leaky_relu
        float p = __expf(e);                    // |e| small: no max-shift needed
        den += p;
        uint4 raw = *(const uint4*)&hb[(size_t)s * F + cl * 8];   // 8 bf16, 16B aligned
        acc[0] += p * __uint_as_float(raw.x << 16);
        acc[1] += p * __uint_as_float(raw.x & 0xffff0000u);
        acc[2] += p * __uint_as_float(raw.y << 16);
        acc[3] += p * __uint_as_float(raw.y & 0xffff0000u);
        acc[4] += p * __uint_as_float(raw.z << 16);
        acc[5] += p * __uint_as_float(raw.z & 0xffff0000u);
        acc[6] += p * __uint_as_float(raw.w << 16);
        acc[7] += p * __uint_as_float(raw.w & 0xffff0000u);
    }

    // reduce the 4 edge groups (same channel mapping in each)
#pragma unroll
    for (int i = 0; i < 8; i++) {
        acc[i] += __shfl_xor(acc[i], 16);
        acc[i] += __shfl_xor(acc[i], 32);
    }
    den += __shfl_xor(den, 16);
    den += __shfl_xor(den, 32);

    if (g == 0) {
        float inv = 1.f / den;
        float v[8];
#pragma unroll
        for (int i = 0; i < 8; i++) {
            v[i] = acc[i] * inv + bias[cl * 8 + i];
            if (apply_elu) v[i] = (v[i] > 0.f) ? v[i] : (__expf(v[i]) - 1.f);
        }
        float4* op = (float4*)&out[(size_t)n * F + cl * 8];
        op[0] = make_float4(v[0], v[1], v[2], v[3]);
        op[1] = make_float4(v[4], v[5], v[6], v[7]);
    }
}

// ---------------- launch ----------------

extern "C" void kernel_launch(void* const* d_in, const int* in_sizes, int n_in,
                              void* d_out, int out_size, void* d_ws, size_t ws_size,
                              hipStream_t stream) {
    const float* x   = (const float*)d_in[0];
    const int*   ei  = (const int*)d_in[1];
    const float* W1  = (const float*)d_in[2];
    const float* as1 = (const float*)d_in[3];
    const float* ad1 = (const float*)d_in[4];
    const float* b1  = (const float*)d_in[5];
    const float* W2  = (const float*)d_in[6];
    const float* as2 = (const float*)d_in[7];
    const float* ad2 = (const float*)d_in[8];
    const float* b2  = (const float*)d_in[9];
    float* out = (float*)d_out;

    char* ws = (char*)d_ws;
    size_t off = 0;
    auto alloc = [&](size_t bytes) {
        void* p = ws + off;
        off += (bytes + 255) & ~(size_t)255;
        return p;
    };
    unsigned short* hb = (unsigned short*)alloc((size_t)NN * F * 2);   // 12.8 MB
    float* als     = (float*)alloc((size_t)NN * HEADS * 4);
    float* ald     = (float*)alloc((size_t)NN * HEADS * 4);
    int*   counts  = (int*)alloc((size_t)NN * 4);
    int*   cursor  = (int*)alloc((size_t)NN * 4);
    int*   row_ptr = (int*)alloc((size_t)(NN + 1) * 4);
    int*   bsum    = (int*)alloc((size_t)NB * 4);
    int*   csr_src = (int*)alloc((size_t)ETOT * 4);       // 3.4 MB

    // CSR build (shared by both layers)
    (void)hipMemsetAsync(counts, 0, (size_t)NN * 4, stream);
    (void)hipMemsetAsync(cursor, 0, (size_t)NN * 4, stream);
    count_k<<<(ETOT + 255) / 256, 256, 0, stream>>>(ei, counts);
    scan_block_k<<<NB, 1024, 0, stream>>>(counts, row_ptr, bsum, NN);
    scan_bsum_k<<<1, 64, 0, stream>>>(bsum, NB);
    add_off_k<<<(NN + 255) / 256, 256, 0, stream>>>(row_ptr, bsum, NN);
    fill_k<<<(ETOT + 255) / 256, 256, 0, stream>>>(ei, row_ptr, cursor, csr_src);

    int gemm_grid = (NN + MT - 1) / MT;
    int agg_grid = (NN + 3) / 4;

    // ---- layer 1 ----
    gemm128_al<<<gemm_grid, 256, 0, stream>>>(x, W1, as1, ad1, hb, als, ald, NN);
    aggregate<<<agg_grid, 256, 0, stream>>>(hb, als, ald, row_ptr, csr_src, b1, out, 1);

    // ---- layer 2 ----
    gemm128_al<<<gemm_grid, 256, 0, stream>>>(out, W2, as2, ad2, hb, als, ald, NN);
    aggregate<<<agg_grid, 256, 0, stream>>>(hb, als, ald, row_ptr, csr_src, b2, out, 0);
}

// Round 6
// 317.870 us; speedup vs baseline: 1.7478x; 1.0881x over previous
//
#include <hip/hip_runtime.h>
#include <hip/hip_bf16.h>

#define NN 50000
#define EE 800000
#define ETOT (EE + NN)
#define F 128
#define HEADS 4
#define MT 64
#define NB ((NN + 1023) / 1024)   // 49 scan chunks

// f32 -> bf16 bits, round-to-nearest-even
__device__ __forceinline__ unsigned short f32_to_bf16(float f) {
    unsigned int u = __float_as_uint(f);
    u += 0x7fffu + ((u >> 16) & 1u);
    return (unsigned short)(u >> 16);
}
__device__ __forceinline__ float bflo(unsigned int u) { return __uint_as_float(u << 16); }
__device__ __forceinline__ float bfhi(unsigned int u) { return __uint_as_float(u & 0xffff0000u); }

// ---------------- fused GEMM (64x128 tile) + logits epilogue + edge count ----------------
// blocks [0, gemm_blocks): GEMM + attention-logit epilogue, bf16 h output
// blocks [gemm_blocks, ...): degree count (layer 1 only; overlaps the GEMM)

__launch_bounds__(256)
__global__ void gemm_count(const float* __restrict__ A, const float* __restrict__ W,
                           const float* __restrict__ a_src, const float* __restrict__ a_dst,
                           unsigned short* __restrict__ Cb, float* __restrict__ als,
                           float* __restrict__ ald, int M,
                           const int* __restrict__ ei, int* __restrict__ counts,
                           int gemm_blocks) {
    __shared__ float xs[MT][F];            // 32 KB
    if ((int)blockIdx.x >= gemm_blocks) {
        int e = (blockIdx.x - gemm_blocks) * 256 + threadIdx.x;
        if (e < ETOT) {
            int dst = (e < EE) ? ei[EE + e] : (e - EE);
            atomicAdd(&counts[dst], 1);
        }
        return;
    }
    int tid = threadIdx.x;
    int row0 = blockIdx.x * MT;

    for (int i = tid; i < MT * F / 4; i += 256) {
        int r  = i >> 5;
        int c4 = i & 31;
        int gr = row0 + r;
        float4 v = (gr < M) ? ((const float4*)A)[(size_t)gr * 32 + c4]
                            : make_float4(0.f, 0.f, 0.f, 0.f);
        ((float4*)&xs[r][0])[c4] = v;
    }
    __syncthreads();

    int cg = (tid & 31) * 4;      // output col
    int rg = (tid >> 5) * 8;      // output row start within tile
    float acc[8][4];
#pragma unroll
    for (int r = 0; r < 8; r++)
#pragma unroll
        for (int j = 0; j < 4; j++) acc[r][j] = 0.f;

#pragma unroll 4
    for (int k = 0; k < F; k += 4) {
        float4 w0 = *(const float4*)&W[(k + 0) * F + cg];
        float4 w1 = *(const float4*)&W[(k + 1) * F + cg];
        float4 w2 = *(const float4*)&W[(k + 2) * F + cg];
        float4 w3 = *(const float4*)&W[(k + 3) * F + cg];
#pragma unroll
        for (int r = 0; r < 8; r++) {
            float4 xv = *(const float4*)&xs[rg + r][k];
            acc[r][0] += xv.x * w0.x + xv.y * w1.x + xv.z * w2.x + xv.w * w3.x;
            acc[r][1] += xv.x * w0.y + xv.y * w1.y + xv.z * w2.y + xv.w * w3.y;
            acc[r][2] += xv.x * w0.z + xv.y * w1.z + xv.z * w2.z + xv.w * w3.z;
            acc[r][3] += xv.x * w0.w + xv.y * w1.w + xv.z * w2.w + xv.w * w3.w;
        }
    }

    int lane = tid & 63;
    int head = (tid & 31) >> 3;
    float4 asv = *(const float4*)&a_src[head * 32 + (lane & 7) * 4];
    float4 adv = *(const float4*)&a_dst[head * 32 + (lane & 7) * 4];
#pragma unroll
    for (int r = 0; r < 8; r++) {
        int gr = row0 + rg + r;
        if (gr < M) {
            ushort4 bv;
            bv.x = f32_to_bf16(acc[r][0]);
            bv.y = f32_to_bf16(acc[r][1]);
            bv.z = f32_to_bf16(acc[r][2]);
            bv.w = f32_to_bf16(acc[r][3]);
            *(ushort4*)&Cb[(size_t)gr * F + cg] = bv;
        }
        float ps = acc[r][0] * asv.x + acc[r][1] * asv.y + acc[r][2] * asv.z + acc[r][3] * asv.w;
        float pd = acc[r][0] * adv.x + acc[r][1] * adv.y + acc[r][2] * adv.z + acc[r][3] * adv.w;
        ps += __shfl_xor(ps, 1); ps += __shfl_xor(ps, 2); ps += __shfl_xor(ps, 4);
        pd += __shfl_xor(pd, 1); pd += __shfl_xor(pd, 2); pd += __shfl_xor(pd, 4);
        if ((lane & 7) == 0 && gr < M) {
            als[gr * HEADS + head] = ps;
            ald[gr * HEADS + head] = pd;
        }
    }
}

// ---------------- CSR scan kernels ----------------

__launch_bounds__(1024)
__global__ void scan_block_k(const int* __restrict__ counts, int* __restrict__ row_ptr,
                             int* __restrict__ bsum, int n) {
    int tid = threadIdx.x;
    int i = blockIdx.x * 1024 + tid;
    int v = (i < n) ? counts[i] : 0;
    int lane = tid & 63;
    int wave = tid >> 6;               // 0..15
    int x = v;
#pragma unroll
    for (int off = 1; off < 64; off <<= 1) {
        int t = __shfl_up(x, off, 64);
        if (lane >= off) x += t;
    }
    __shared__ int wsum[16];
    if (lane == 63) wsum[wave] = x;
    __syncthreads();
    if (wave == 0) {
        int w = (lane < 16) ? wsum[lane] : 0;
#pragma unroll
        for (int off = 1; off < 16; off <<= 1) {
            int t = __shfl_up(w, off, 64);
            if (lane >= off) w += t;
        }
        if (lane < 16) wsum[lane] = w;
    }
    __syncthreads();
    int base = (wave > 0) ? wsum[wave - 1] : 0;
    int incl = base + x;
    if (i < n) row_ptr[i] = incl - v;          // exclusive within chunk
    if (tid == 1023) bsum[blockIdx.x] = incl;  // chunk total
}

// fused: every block scans the 49 chunk totals locally, then adds offsets
__launch_bounds__(256)
__global__ void scan_add_k(int* __restrict__ row_ptr, const int* __restrict__ bsum, int n) {
    __shared__ int off_s[NB];
    if (threadIdx.x < 64) {
        int lane = threadIdx.x;
        int v = (lane < NB) ? bsum[lane] : 0;
        int x = v;
#pragma unroll
        for (int o = 1; o < 64; o <<= 1) {
            int t = __shfl_up(x, o, 64);
            if (lane >= o) x += t;
        }
        if (lane < NB) off_s[lane] = x - v;
    }
    __syncthreads();
    int i = blockIdx.x * blockDim.x + threadIdx.x;
    if (i < n) row_ptr[i] += off_s[i >> 10];
    if (i == 0) row_ptr[n] = ETOT;
}

// fill: atomicSub on counts serves as cursor (within-bucket order irrelevant)
__global__ void fill_k(const int* __restrict__ ei, const int* __restrict__ row_ptr,
                       int* __restrict__ counts, int* __restrict__ csr_src) {
    int e = blockIdx.x * blockDim.x + threadIdx.x;
    if (e >= ETOT) return;
    int src, dst;
    if (e < EE) { src = ei[e]; dst = ei[EE + e]; }
    else        { src = e - EE; dst = e - EE; }
    int c = atomicSub(&counts[dst], 1);
    csr_src[row_ptr[dst] + c - 1] = src;
}

// ---------------- softmax + aggregate: wave/node, 4 groups x 16 lanes, 2-edge pipeline ----

__launch_bounds__(256)
__global__ void aggregate(const unsigned short* __restrict__ hb, const float* __restrict__ als,
                          const float* __restrict__ ald, const int* __restrict__ row_ptr,
                          const int* __restrict__ csr_src, const float* __restrict__ bias,
                          float* __restrict__ out, int apply_elu) {
    int wave = threadIdx.x >> 6;
    int n = blockIdx.x * 4 + wave;
    if (n >= NN) return;
    int lane = threadIdx.x & 63;
    int g  = lane >> 4;           // edge group 0..3
    int cl = lane & 15;           // channels cl*8 .. cl*8+7
    int head = cl >> 2;
    float aldv = ald[n * HEADS + head];
    int jb = row_ptr[n], je = row_ptr[n + 1];

    float acc[8];
#pragma unroll
    for (int i = 0; i < 8; i++) acc[i] = 0.f;
    float den = 0.f;

    int j = jb + g;
    // two independent edge-chains per iteration
    for (; j + 4 < je; j += 8) {
        int s0 = csr_src[j];
        int s1 = csr_src[j + 4];
        float e0 = als[s0 * HEADS + head] + aldv;
        float e1 = als[s1 * HEADS + head] + aldv;
        uint4 r0 = *(const uint4*)&hb[(size_t)s0 * F + cl * 8];
        uint4 r1 = *(const uint4*)&hb[(size_t)s1 * F + cl * 8];
        e0 = (e0 > 0.f) ? e0 : 0.2f * e0;
        e1 = (e1 > 0.f) ? e1 : 0.2f * e1;
        float p0 = __expf(e0);
        float p1 = __expf(e1);
        den += p0 + p1;
        acc[0] += p0 * bflo(r0.x); acc[1] += p0 * bfhi(r0.x);
        acc[2] += p0 * bflo(r0.y); acc[3] += p0 * bfhi(r0.y);
        acc[4] += p0 * bflo(r0.z); acc[5] += p0 * bfhi(r0.z);
        acc[6] += p0 * bflo(r0.w); acc[7] += p0 * bfhi(r0.w);
        acc[0] += p1 * bflo(r1.x); acc[1] += p1 * bfhi(r1.x);
        acc[2] += p1 * bflo(r1.y); acc[3] += p1 * bfhi(r1.y);
        acc[4] += p1 * bflo(r1.z); acc[5] += p1 * bfhi(r1.z);
        acc[6] += p1 * bflo(r1.w); acc[7] += p1 * bfhi(r1.w);
    }
    if (j < je) {                 // tail (at most one per group)
        int s = csr_src[j];
        float e = als[s * HEADS + head] + aldv;
        uint4 raw = *(const uint4*)&hb[(size_t)s * F + cl * 8];
        e = (e > 0.f) ? e : 0.2f * e;
        float p = __expf(e);
        den += p;
        acc[0] += p * bflo(raw.x); acc[1] += p * bfhi(raw.x);
        acc[2] += p * bflo(raw.y); acc[3] += p * bfhi(raw.y);
        acc[4] += p * bflo(raw.z); acc[5] += p * bfhi(raw.z);
        acc[6] += p * bflo(raw.w); acc[7] += p * bfhi(raw.w);
    }

    // reduce the 4 edge groups
#pragma unroll
    for (int i = 0; i < 8; i++) {
        acc[i] += __shfl_xor(acc[i], 16);
        acc[i] += __shfl_xor(acc[i], 32);
    }
    den += __shfl_xor(den, 16);
    den += __shfl_xor(den, 32);

    if (g == 0) {
        float inv = 1.f / den;
        float v[8];
#pragma unroll
        for (int i = 0; i < 8; i++) {
            v[i] = acc[i] * inv + bias[cl * 8 + i];
            if (apply_elu) v[i] = (v[i] > 0.f) ? v[i] : (__expf(v[i]) - 1.f);
        }
        float4* op = (float4*)&out[(size_t)n * F + cl * 8];
        op[0] = make_float4(v[0], v[1], v[2], v[3]);
        op[1] = make_float4(v[4], v[5], v[6], v[7]);
    }
}

// ---------------- launch ----------------

extern "C" void kernel_launch(void* const* d_in, const int* in_sizes, int n_in,
                              void* d_out, int out_size, void* d_ws, size_t ws_size,
                              hipStream_t stream) {
    const float* x   = (const float*)d_in[0];
    const int*   ei  = (const int*)d_in[1];
    const float* W1  = (const float*)d_in[2];
    const float* as1 = (const float*)d_in[3];
    const float* ad1 = (const float*)d_in[4];
    const float* b1  = (const float*)d_in[5];
    const float* W2  = (const float*)d_in[6];
    const float* as2 = (const float*)d_in[7];
    const float* ad2 = (const float*)d_in[8];
    const float* b2  = (const float*)d_in[9];
    float* out = (float*)d_out;

    char* ws = (char*)d_ws;
    size_t off = 0;
    auto alloc = [&](size_t bytes) {
        void* p = ws + off;
        off += (bytes + 255) & ~(size_t)255;
        return p;
    };
    unsigned short* hb = (unsigned short*)alloc((size_t)NN * F * 2);   // 12.8 MB
    float* als     = (float*)alloc((size_t)NN * HEADS * 4);
    float* ald     = (float*)alloc((size_t)NN * HEADS * 4);
    int*   counts  = (int*)alloc((size_t)NN * 4);
    int*   row_ptr = (int*)alloc((size_t)(NN + 1) * 4);
    int*   bsum    = (int*)alloc((size_t)NB * 4);
    int*   csr_src = (int*)alloc((size_t)ETOT * 4);       // 3.4 MB

    int GG = (NN + MT - 1) / MT;           // 782 GEMM blocks
    int CG = (ETOT + 255) / 256;           // 3321 count blocks
    int agg_grid = (NN + 3) / 4;

    (void)hipMemsetAsync(counts, 0, (size_t)NN * 4, stream);

    // ---- layer 1 GEMM + logits, with degree-count overlapped ----
    gemm_count<<<GG + CG, 256, 0, stream>>>(x, W1, as1, ad1, hb, als, ald, NN,
                                            ei, counts, GG);
    scan_block_k<<<NB, 1024, 0, stream>>>(counts, row_ptr, bsum, NN);
    scan_add_k<<<(NN + 255) / 256, 256, 0, stream>>>(row_ptr, bsum, NN);
    fill_k<<<CG, 256, 0, stream>>>(ei, row_ptr, counts, csr_src);
    aggregate<<<agg_grid, 256, 0, stream>>>(hb, als, ald, row_ptr, csr_src, b1, out, 1);

    // ---- layer 2 ----
    gemm_count<<<GG, 256, 0, stream>>>(out, W2, as2, ad2, hb, als, ald, NN,
                                       (const int*)nullptr, (int*)nullptr, GG);
    aggregate<<<agg_grid, 256, 0, stream>>>(hb, als, ald, row_ptr, csr_src, b2, out, 0);
}

// Round 7
// 314.025 us; speedup vs baseline: 1.7692x; 1.0122x over previous
//
#include <hip/hip_runtime.h>
#include <hip/hip_bf16.h>

#define NN 50000
#define EE 800000
#define ETOT (EE + NN)
#define F 128
#define HEADS 4
#define MT 64
#define NB ((NN + 1023) / 1024)   // 49 scan chunks

typedef __bf16 bf16x8 __attribute__((ext_vector_type(8)));
typedef float  f32x4  __attribute__((ext_vector_type(4)));

// f32 -> bf16 bits, round-to-nearest-even
__device__ __forceinline__ unsigned short f32_to_bf16(float f) {
    unsigned int u = __float_as_uint(f);
    u += 0x7fffu + ((u >> 16) & 1u);
    return (unsigned short)(u >> 16);
}
__device__ __forceinline__ float bf16bits_to_f32(unsigned short s) {
    return __uint_as_float(((unsigned int)s) << 16);
}
__device__ __forceinline__ float bflo(unsigned int u) { return __uint_as_float(u << 16); }
__device__ __forceinline__ float bfhi(unsigned int u) { return __uint_as_float(u & 0xffff0000u); }

union BU { unsigned short u[8]; bf16x8 v; };

// ---------------- W pre-pack into MFMA B-fragment order, split hi/lo ----------------
// layout: wf[((which*2 + hilo)*2048 + (kt*8+nt)*64 + lane)*8 + j]
// B-frag: lane holds B[k = kt*32 + (lane>>4)*8 + j][n = nt*16 + (lane&15)]

__global__ void wpack_k(const float* __restrict__ W1, const float* __restrict__ W2,
                        unsigned short* __restrict__ wf) {
    int t = blockIdx.x * blockDim.x + threadIdx.x;
    if (t >= 2 * 2048) return;
    int which = t >> 11;
    int rem = t & 2047;
    int lane = rem & 63;
    int tile = rem >> 6;          // kt*8+nt
    int kt = tile >> 3, nt = tile & 7;
    int q = lane >> 4, c = lane & 15;
    const float* W = which ? W2 : W1;
    BU vh, vl;
#pragma unroll
    for (int j = 0; j < 8; j++) {
        float w = W[(kt * 32 + q * 8 + j) * F + nt * 16 + c];
        unsigned short hb = f32_to_bf16(w);
        vh.u[j] = hb;
        vl.u[j] = f32_to_bf16(w - bf16bits_to_f32(hb));
    }
    size_t base_h = ((size_t)(which * 2 + 0) * 2048 + tile * 64 + lane) * 8;
    size_t base_l = ((size_t)(which * 2 + 1) * 2048 + tile * 64 + lane) * 8;
    *(bf16x8*)&wf[base_h] = vh.v;
    *(bf16x8*)&wf[base_l] = vl.v;
}

// ---------------- MFMA GEMM (64 rows/block, wave=16 rows) + logits + bf16 h out ------
// blocks >= gemm_blocks do the degree count (layer 1 only; overlaps the GEMM)

__launch_bounds__(256)
__global__ void gemm_mfma(const float* __restrict__ A, const unsigned short* __restrict__ wf,
                          const float* __restrict__ a_src, const float* __restrict__ a_dst,
                          unsigned short* __restrict__ Cb, float* __restrict__ als,
                          float* __restrict__ ald, int M,
                          const int* __restrict__ ei, int* __restrict__ counts,
                          int gemm_blocks) {
    __shared__ float lds[4][16 * 132];
    if ((int)blockIdx.x >= gemm_blocks) {
        int e = (blockIdx.x - gemm_blocks) * 256 + threadIdx.x;
        if (e < ETOT) {
            int dst = (e < EE) ? ei[EE + e] : (e - EE);
            atomicAdd(&counts[dst], 1);
        }
        return;
    }
    int tid = threadIdx.x;
    int w = tid >> 6, lane = tid & 63;
    int m = lane & 15, q = lane >> 4;
    int row0 = blockIdx.x * MT + w * 16;

    int ar = row0 + m; if (ar >= M) ar = 0;          // clamp; stores guarded
    const float* arow = A + (size_t)ar * F + q * 8;
    const unsigned short* wfh = wf;
    const unsigned short* wfl = wf + 2048 * 8;

    f32x4 acc[8];
#pragma unroll
    for (int nt = 0; nt < 8; nt++) acc[nt] = (f32x4){0.f, 0.f, 0.f, 0.f};

#pragma unroll
    for (int kt = 0; kt < 4; kt++) {
        float4 a0 = *(const float4*)(arow + kt * 32);
        float4 a1 = *(const float4*)(arow + kt * 32 + 4);
        float av[8] = {a0.x, a0.y, a0.z, a0.w, a1.x, a1.y, a1.z, a1.w};
        BU ah, al;
#pragma unroll
        for (int j = 0; j < 8; j++) {
            unsigned short hb = f32_to_bf16(av[j]);
            ah.u[j] = hb;
            al.u[j] = f32_to_bf16(av[j] - bf16bits_to_f32(hb));
        }
#pragma unroll
        for (int nt = 0; nt < 8; nt++) {
            size_t bo = ((size_t)(kt * 8 + nt) * 64 + lane) * 8;
            bf16x8 bh = *(const bf16x8*)&wfh[bo];
            bf16x8 bl = *(const bf16x8*)&wfl[bo];
            acc[nt] = __builtin_amdgcn_mfma_f32_16x16x32_bf16(ah.v, bh, acc[nt], 0, 0, 0);
            acc[nt] = __builtin_amdgcn_mfma_f32_16x16x32_bf16(al.v, bh, acc[nt], 0, 0, 0);
            acc[nt] = __builtin_amdgcn_mfma_f32_16x16x32_bf16(ah.v, bl, acc[nt], 0, 0, 0);
        }
    }

    // C/D layout: col = lane&15, row = q*4+reg  ->  LDS transpose (pad 132)
    float* L = lds[w];
#pragma unroll
    for (int nt = 0; nt < 8; nt++)
#pragma unroll
        for (int r = 0; r < 4; r++)
            L[(q * 4 + r) * 132 + nt * 16 + m] = acc[nt][r];
    __syncthreads();

    int rr = lane >> 2;            // row within wave tile
    int head = lane & 3;
    int c0 = head * 32;            // this lane owns head's 32 channels of row rr
    int gr = row0 + rr;
    float v[32];
#pragma unroll
    for (int i = 0; i < 8; i++)
        *(float4*)&v[i * 4] = *(const float4*)&L[rr * 132 + c0 + i * 4];

    if (gr < M) {
#pragma unroll
        for (int i = 0; i < 4; i++) {
            uint4 pk;
            pk.x = (unsigned)f32_to_bf16(v[i * 8 + 0]) | ((unsigned)f32_to_bf16(v[i * 8 + 1]) << 16);
            pk.y = (unsigned)f32_to_bf16(v[i * 8 + 2]) | ((unsigned)f32_to_bf16(v[i * 8 + 3]) << 16);
            pk.z = (unsigned)f32_to_bf16(v[i * 8 + 4]) | ((unsigned)f32_to_bf16(v[i * 8 + 5]) << 16);
            pk.w = (unsigned)f32_to_bf16(v[i * 8 + 6]) | ((unsigned)f32_to_bf16(v[i * 8 + 7]) << 16);
            *(uint4*)&Cb[(size_t)gr * F + c0 + i * 8] = pk;
        }
        float ps = 0.f, pd = 0.f;
#pragma unroll
        for (int i = 0; i < 32; i++) {
            ps += v[i] * a_src[c0 + i];
            pd += v[i] * a_dst[c0 + i];
        }
        als[gr * HEADS + head] = ps;
        ald[gr * HEADS + head] = pd;
    }
}

// ---------------- CSR scan kernels ----------------

__launch_bounds__(1024)
__global__ void scan_block_k(const int* __restrict__ counts, int* __restrict__ row_ptr,
                             int* __restrict__ bsum, int n) {
    int tid = threadIdx.x;
    int i = blockIdx.x * 1024 + tid;
    int v = (i < n) ? counts[i] : 0;
    int lane = tid & 63;
    int wave = tid >> 6;
    int x = v;
#pragma unroll
    for (int off = 1; off < 64; off <<= 1) {
        int t = __shfl_up(x, off, 64);
        if (lane >= off) x += t;
    }
    __shared__ int wsum[16];
    if (lane == 63) wsum[wave] = x;
    __syncthreads();
    if (wave == 0) {
        int w = (lane < 16) ? wsum[lane] : 0;
#pragma unroll
        for (int off = 1; off < 16; off <<= 1) {
            int t = __shfl_up(w, off, 64);
            if (lane >= off) w += t;
        }
        if (lane < 16) wsum[lane] = w;
    }
    __syncthreads();
    int base = (wave > 0) ? wsum[wave - 1] : 0;
    int incl = base + x;
    if (i < n) row_ptr[i] = incl - v;
    if (tid == 1023) bsum[blockIdx.x] = incl;
}

__launch_bounds__(256)
__global__ void scan_add_k(int* __restrict__ row_ptr, const int* __restrict__ bsum, int n) {
    __shared__ int off_s[NB];
    if (threadIdx.x < 64) {
        int lane = threadIdx.x;
        int v = (lane < NB) ? bsum[lane] : 0;
        int x = v;
#pragma unroll
        for (int o = 1; o < 64; o <<= 1) {
            int t = __shfl_up(x, o, 64);
            if (lane >= o) x += t;
        }
        if (lane < NB) off_s[lane] = x - v;
    }
    __syncthreads();
    int i = blockIdx.x * blockDim.x + threadIdx.x;
    if (i < n) row_ptr[i] += off_s[i >> 10];
    if (i == 0) row_ptr[n] = ETOT;
}

__global__ void fill_k(const int* __restrict__ ei, const int* __restrict__ row_ptr,
                       int* __restrict__ counts, int* __restrict__ csr_src) {
    int e = blockIdx.x * blockDim.x + threadIdx.x;
    if (e >= ETOT) return;
    int src, dst;
    if (e < EE) { src = ei[e]; dst = ei[EE + e]; }
    else        { src = e - EE; dst = e - EE; }
    int c = atomicSub(&counts[dst], 1);
    csr_src[row_ptr[dst] + c - 1] = src;
}

// ---------------- softmax + aggregate: wave/node, 4 groups x 16 lanes, 2-edge ILP ----

__launch_bounds__(256)
__global__ void aggregate(const unsigned short* __restrict__ hb, const float* __restrict__ als,
                          const float* __restrict__ ald, const int* __restrict__ row_ptr,
                          const int* __restrict__ csr_src, const float* __restrict__ bias,
                          float* __restrict__ out, int apply_elu) {
    int wave = threadIdx.x >> 6;
    int n = blockIdx.x * 4 + wave;
    if (n >= NN) return;
    int lane = threadIdx.x & 63;
    int g  = lane >> 4;
    int cl = lane & 15;
    int head = cl >> 2;
    float aldv = ald[n * HEADS + head];
    int jb = row_ptr[n], je = row_ptr[n + 1];

    float acc[8];
#pragma unroll
    for (int i = 0; i < 8; i++) acc[i] = 0.f;
    float den = 0.f;

    int j = jb + g;
    for (; j + 4 < je; j += 8) {
        int s0 = csr_src[j];
        int s1 = csr_src[j + 4];
        float e0 = als[s0 * HEADS + head] + aldv;
        float e1 = als[s1 * HEADS + head] + aldv;
        uint4 r0 = *(const uint4*)&hb[(size_t)s0 * F + cl * 8];
        uint4 r1 = *(const uint4*)&hb[(size_t)s1 * F + cl * 8];
        e0 = (e0 > 0.f) ? e0 : 0.2f * e0;
        e1 = (e1 > 0.f) ? e1 : 0.2f * e1;
        float p0 = __expf(e0);
        float p1 = __expf(e1);
        den += p0 + p1;
        acc[0] += p0 * bflo(r0.x); acc[1] += p0 * bfhi(r0.x);
        acc[2] += p0 * bflo(r0.y); acc[3] += p0 * bfhi(r0.y);
        acc[4] += p0 * bflo(r0.z); acc[5] += p0 * bfhi(r0.z);
        acc[6] += p0 * bflo(r0.w); acc[7] += p0 * bfhi(r0.w);
        acc[0] += p1 * bflo(r1.x); acc[1] += p1 * bfhi(r1.x);
        acc[2] += p1 * bflo(r1.y); acc[3] += p1 * bfhi(r1.y);
        acc[4] += p1 * bflo(r1.z); acc[5] += p1 * bfhi(r1.z);
        acc[6] += p1 * bflo(r1.w); acc[7] += p1 * bfhi(r1.w);
    }
    if (j < je) {
        int s = csr_src[j];
        float e = als[s * HEADS + head] + aldv;
        uint4 raw = *(const uint4*)&hb[(size_t)s * F + cl * 8];
        e = (e > 0.f) ? e : 0.2f * e;
        float p = __expf(e);
        den += p;
        acc[0] += p * bflo(raw.x); acc[1] += p * bfhi(raw.x);
        acc[2] += p * bflo(raw.y); acc[3] += p * bfhi(raw.y);
        acc[4] += p * bflo(raw.z); acc[5] += p * bfhi(raw.z);
        acc[6] += p * bflo(raw.w); acc[7] += p * bfhi(raw.w);
    }

#pragma unroll
    for (int i = 0; i < 8; i++) {
        acc[i] += __shfl_xor(acc[i], 16);
        acc[i] += __shfl_xor(acc[i], 32);
    }
    den += __shfl_xor(den, 16);
    den += __shfl_xor(den, 32);

    if (g == 0) {
        float inv = 1.f / den;
        float v[8];
#pragma unroll
        for (int i = 0; i < 8; i++) {
            v[i] = acc[i] * inv + bias[cl * 8 + i];
            if (apply_elu) v[i] = (v[i] > 0.f) ? v[i] : (__expf(v[i]) - 1.f);
        }
        float4* op = (float4*)&out[(size_t)n * F + cl * 8];
        op[0] = make_float4(v[0], v[1], v[2], v[3]);
        op[1] = make_float4(v[4], v[5], v[6], v[7]);
    }
}

// ---------------- launch ----------------

extern "C" void kernel_launch(void* const* d_in, const int* in_sizes, int n_in,
                              void* d_out, int out_size, void* d_ws, size_t ws_size,
                              hipStream_t stream) {
    const float* x   = (const float*)d_in[0];
    const int*   ei  = (const int*)d_in[1];
    const float* W1  = (const float*)d_in[2];
    const float* as1 = (const float*)d_in[3];
    const float* ad1 = (const float*)d_in[4];
    const float* b1  = (const float*)d_in[5];
    const float* W2  = (const float*)d_in[6];
    const float* as2 = (const float*)d_in[7];
    const float* ad2 = (const float*)d_in[8];
    const float* b2  = (const float*)d_in[9];
    float* out = (float*)d_out;

    char* ws = (char*)d_ws;
    size_t off = 0;
    auto alloc = [&](size_t bytes) {
        void* p = ws + off;
        off += (bytes + 255) & ~(size_t)255;
        return p;
    };
    unsigned short* hb = (unsigned short*)alloc((size_t)NN * F * 2);   // 12.8 MB
    float* als     = (float*)alloc((size_t)NN * HEADS * 4);
    float* ald     = (float*)alloc((size_t)NN * HEADS * 4);
    int*   counts  = (int*)alloc((size_t)NN * 4);
    int*   row_ptr = (int*)alloc((size_t)(NN + 1) * 4);
    int*   bsum    = (int*)alloc((size_t)NB * 4);
    int*   csr_src = (int*)alloc((size_t)ETOT * 4);       // 3.4 MB
    unsigned short* wf = (unsigned short*)alloc((size_t)4 * 2048 * 8 * 2);  // 128 KB

    int GG = (NN + MT - 1) / MT;           // 782 GEMM blocks
    int CG = (ETOT + 255) / 256;           // 3321 count blocks
    int agg_grid = (NN + 3) / 4;

    (void)hipMemsetAsync(counts, 0, (size_t)NN * 4, stream);
    wpack_k<<<16, 256, 0, stream>>>(W1, W2, wf);

    // ---- layer 1 GEMM (MFMA split-precision) + logits, degree-count overlapped ----
    gemm_mfma<<<GG + CG, 256, 0, stream>>>(x, wf, as1, ad1, hb, als, ald, NN,
                                           ei, counts, GG);
    scan_block_k<<<NB, 1024, 0, stream>>>(counts, row_ptr, bsum, NN);
    scan_add_k<<<(NN + 255) / 256, 256, 0, stream>>>(row_ptr, bsum, NN);
    fill_k<<<CG, 256, 0, stream>>>(ei, row_ptr, counts, csr_src);
    aggregate<<<agg_grid, 256, 0, stream>>>(hb, als, ald, row_ptr, csr_src, b1, out, 1);

    // ---- layer 2 ----
    gemm_mfma<<<GG, 256, 0, stream>>>(out, wf + (size_t)2 * 2048 * 8, as2, ad2, hb, als, ald, NN,
                                      (const int*)nullptr, (int*)nullptr, GG);
    aggregate<<<agg_grid, 256, 0, stream>>>(hb, als, ald, row_ptr, csr_src, b2, out, 0);
}

// Round 8
// 296.968 us; speedup vs baseline: 1.8708x; 1.0574x over previous
//
#include <hip/hip_runtime.h>
#include <hip/hip_bf16.h>

#define NN 50000
#define EE 800000
#define ETOT (EE + NN)
#define F 128
#define HEADS 4
#define MT 64
#define NB ((NN + 1023) / 1024)   // 49 scan chunks

typedef __bf16 bf16x8 __attribute__((ext_vector_type(8)));
typedef float  f32x4  __attribute__((ext_vector_type(4)));

// f32 -> bf16 bits, round-to-nearest-even
__device__ __forceinline__ unsigned short f32_to_bf16(float f) {
    unsigned int u = __float_as_uint(f);
    u += 0x7fffu + ((u >> 16) & 1u);
    return (unsigned short)(u >> 16);
}
__device__ __forceinline__ float bf16bits_to_f32(unsigned short s) {
    return __uint_as_float(((unsigned int)s) << 16);
}
__device__ __forceinline__ float bflo(unsigned int u) { return __uint_as_float(u << 16); }
__device__ __forceinline__ float bfhi(unsigned int u) { return __uint_as_float(u & 0xffff0000u); }

union BU { unsigned short u[8]; bf16x8 v; };

// ---------------- W pre-pack into MFMA B-fragment order, split hi/lo ----------------
// per layer: 64 KB contiguous [hi 32KB | lo 32KB]
// B-frag: lane holds B[k = kt*32 + (lane>>4)*8 + j][n = nt*16 + (lane&15)]

__global__ void wpack_k(const float* __restrict__ W1, const float* __restrict__ W2,
                        unsigned short* __restrict__ wf) {
    int t = blockIdx.x * blockDim.x + threadIdx.x;
    if (t >= 2 * 2048) return;
    int which = t >> 11;
    int rem = t & 2047;
    int lane = rem & 63;
    int tile = rem >> 6;          // kt*8+nt
    int kt = tile >> 3, nt = tile & 7;
    int q = lane >> 4, c = lane & 15;
    const float* W = which ? W2 : W1;
    BU vh, vl;
#pragma unroll
    for (int j = 0; j < 8; j++) {
        float w = W[(kt * 32 + q * 8 + j) * F + nt * 16 + c];
        unsigned short hb = f32_to_bf16(w);
        vh.u[j] = hb;
        vl.u[j] = f32_to_bf16(w - bf16bits_to_f32(hb));
    }
    size_t base_h = ((size_t)(which * 2 + 0) * 2048 + tile * 64 + lane) * 8;
    size_t base_l = ((size_t)(which * 2 + 1) * 2048 + tile * 64 + lane) * 8;
    *(bf16x8*)&wf[base_h] = vh.v;
    *(bf16x8*)&wf[base_l] = vl.v;
}

// ---------------- MFMA GEMM, W staged in LDS ----------------
// blocks >= gemm_blocks do the degree count (layer 1 only; overlaps the GEMM)

__launch_bounds__(256)
__global__ void gemm_mfma(const float* __restrict__ A, const unsigned short* __restrict__ wf,
                          const float* __restrict__ a_src, const float* __restrict__ a_dst,
                          unsigned short* __restrict__ Cb, float* __restrict__ als,
                          float* __restrict__ ald, int M,
                          const int* __restrict__ ei, int* __restrict__ counts,
                          int gemm_blocks) {
    __shared__ unsigned char smem[65536];     // W hi+lo; epilogue aliases it
    if ((int)blockIdx.x >= gemm_blocks) {
        int e = (blockIdx.x - gemm_blocks) * 256 + threadIdx.x;
        if (e < ETOT) {
            int dst = (e < EE) ? ei[EE + e] : (e - EE);
            atomicAdd(&counts[dst], 1);
        }
        return;
    }
    int tid = threadIdx.x;
    int w = tid >> 6, lane = tid & 63;
    int m = lane & 15, q = lane >> 4;
    int row0 = blockIdx.x * MT + w * 16;

    // stage 64 KB of packed W into LDS (coalesced 16B per lane)
    {
        const uint4* src = (const uint4*)wf;
        uint4* dst = (uint4*)smem;
#pragma unroll
        for (int i = 0; i < 16; i++) dst[tid + i * 256] = src[tid + i * 256];
    }
    __syncthreads();

    int ar = row0 + m; if (ar >= M) ar = 0;          // clamp; stores guarded
    const float* arow = A + (size_t)ar * F + q * 8;
    const unsigned short* lds_h = (const unsigned short*)smem;            // hi
    const unsigned short* lds_l = (const unsigned short*)(smem + 32768);  // lo

    f32x4 acc[8];
#pragma unroll
    for (int nt = 0; nt < 8; nt++) acc[nt] = (f32x4){0.f, 0.f, 0.f, 0.f};

#pragma unroll
    for (int kt = 0; kt < 4; kt++) {
        float4 a0 = *(const float4*)(arow + kt * 32);
        float4 a1 = *(const float4*)(arow + kt * 32 + 4);
        float av[8] = {a0.x, a0.y, a0.z, a0.w, a1.x, a1.y, a1.z, a1.w};
        BU ah, al;
#pragma unroll
        for (int j = 0; j < 8; j++) {
            unsigned short hb = f32_to_bf16(av[j]);
            ah.u[j] = hb;
            al.u[j] = f32_to_bf16(av[j] - bf16bits_to_f32(hb));
        }
#pragma unroll
        for (int nt = 0; nt < 8; nt++) {
            int bo = ((kt * 8 + nt) * 64 + lane) * 8;
            bf16x8 bh = *(const bf16x8*)&lds_h[bo];
            bf16x8 bl = *(const bf16x8*)&lds_l[bo];
            acc[nt] = __builtin_amdgcn_mfma_f32_16x16x32_bf16(ah.v, bh, acc[nt], 0, 0, 0);
            acc[nt] = __builtin_amdgcn_mfma_f32_16x16x32_bf16(al.v, bh, acc[nt], 0, 0, 0);
            acc[nt] = __builtin_amdgcn_mfma_f32_16x16x32_bf16(ah.v, bl, acc[nt], 0, 0, 0);
        }
    }
    __syncthreads();   // all waves done reading W from LDS; safe to reuse as epilogue buffer

    // C/D layout: col = lane&15, row = q*4+reg  ->  LDS transpose (pad 132)
    float* L = (float*)smem + w * (16 * 132);
#pragma unroll
    for (int nt = 0; nt < 8; nt++)
#pragma unroll
        for (int r = 0; r < 4; r++)
            L[(q * 4 + r) * 132 + nt * 16 + m] = acc[nt][r];
    // within-wave RAW on LDS: compiler inserts lgkmcnt wait

    int rr = lane >> 2;            // row within wave tile
    int head = lane & 3;
    int c0 = head * 32;            // this lane owns head's 32 channels of row rr
    int gr = row0 + rr;
    float v[32];
#pragma unroll
    for (int i = 0; i < 8; i++)
        *(float4*)&v[i * 4] = *(const float4*)&L[rr * 132 + c0 + i * 4];

    if (gr < M) {
#pragma unroll
        for (int i = 0; i < 4; i++) {
            uint4 pk;
            pk.x = (unsigned)f32_to_bf16(v[i * 8 + 0]) | ((unsigned)f32_to_bf16(v[i * 8 + 1]) << 16);
            pk.y = (unsigned)f32_to_bf16(v[i * 8 + 2]) | ((unsigned)f32_to_bf16(v[i * 8 + 3]) << 16);
            pk.z = (unsigned)f32_to_bf16(v[i * 8 + 4]) | ((unsigned)f32_to_bf16(v[i * 8 + 5]) << 16);
            pk.w = (unsigned)f32_to_bf16(v[i * 8 + 6]) | ((unsigned)f32_to_bf16(v[i * 8 + 7]) << 16);
            *(uint4*)&Cb[(size_t)gr * F + c0 + i * 8] = pk;
        }
        float ps = 0.f, pd = 0.f;
#pragma unroll
        for (int i = 0; i < 32; i++) {
            ps += v[i] * a_src[c0 + i];
            pd += v[i] * a_dst[c0 + i];
        }
        als[gr * HEADS + head] = ps;
        ald[gr * HEADS + head] = pd;
    }
}

// ---------------- CSR scan kernels ----------------

__launch_bounds__(1024)
__global__ void scan_block_k(const int* __restrict__ counts, int* __restrict__ row_ptr,
                             int* __restrict__ bsum, int n) {
    int tid = threadIdx.x;
    int i = blockIdx.x * 1024 + tid;
    int v = (i < n) ? counts[i] : 0;
    int lane = tid & 63;
    int wave = tid >> 6;
    int x = v;
#pragma unroll
    for (int off = 1; off < 64; off <<= 1) {
        int t = __shfl_up(x, off, 64);
        if (lane >= off) x += t;
    }
    __shared__ int wsum[16];
    if (lane == 63) wsum[wave] = x;
    __syncthreads();
    if (wave == 0) {
        int w = (lane < 16) ? wsum[lane] : 0;
#pragma unroll
        for (int off = 1; off < 16; off <<= 1) {
            int t = __shfl_up(w, off, 64);
            if (lane >= off) w += t;
        }
        if (lane < 16) wsum[lane] = w;
    }
    __syncthreads();
    int base = (wave > 0) ? wsum[wave - 1] : 0;
    int incl = base + x;
    if (i < n) row_ptr[i] = incl - v;
    if (tid == 1023) bsum[blockIdx.x] = incl;
}

__launch_bounds__(256)
__global__ void scan_add_k(int* __restrict__ row_ptr, const int* __restrict__ bsum, int n) {
    __shared__ int off_s[NB];
    if (threadIdx.x < 64) {
        int lane = threadIdx.x;
        int v = (lane < NB) ? bsum[lane] : 0;
        int x = v;
#pragma unroll
        for (int o = 1; o < 64; o <<= 1) {
            int t = __shfl_up(x, o, 64);
            if (lane >= o) x += t;
        }
        if (lane < NB) off_s[lane] = x - v;
    }
    __syncthreads();
    int i = blockIdx.x * blockDim.x + threadIdx.x;
    if (i < n) row_ptr[i] += off_s[i >> 10];
    if (i == 0) row_ptr[n] = ETOT;
}

__global__ void fill_k(const int* __restrict__ ei, const int* __restrict__ row_ptr,
                       int* __restrict__ counts, int* __restrict__ csr_src) {
    int e = blockIdx.x * blockDim.x + threadIdx.x;
    if (e >= ETOT) return;
    int src, dst;
    if (e < EE) { src = ei[e]; dst = ei[EE + e]; }
    else        { src = e - EE; dst = e - EE; }
    int c = atomicSub(&counts[dst], 1);
    csr_src[row_ptr[dst] + c - 1] = src;
}

// ---------------- softmax + aggregate: wave/node, 4 groups x 16 lanes, 2-edge ILP ----

__launch_bounds__(256)
__global__ void aggregate(const unsigned short* __restrict__ hb, const float* __restrict__ als,
                          const float* __restrict__ ald, const int* __restrict__ row_ptr,
                          const int* __restrict__ csr_src, const float* __restrict__ bias,
                          float* __restrict__ out, int apply_elu) {
    int wave = threadIdx.x >> 6;
    int n = blockIdx.x * 4 + wave;
    if (n >= NN) return;
    int lane = threadIdx.x & 63;
    int g  = lane >> 4;
    int cl = lane & 15;
    int head = cl >> 2;
    float aldv = ald[n * HEADS + head];
    int jb = row_ptr[n], je = row_ptr[n + 1];

    float acc[8];
#pragma unroll
    for (int i = 0; i < 8; i++) acc[i] = 0.f;
    float den = 0.f;

    int j = jb + g;
    for (; j + 4 < je; j += 8) {
        int s0 = csr_src[j];
        int s1 = csr_src[j + 4];
        float e0 = als[s0 * HEADS + head] + aldv;
        float e1 = als[s1 * HEADS + head] + aldv;
        uint4 r0 = *(const uint4*)&hb[(size_t)s0 * F + cl * 8];
        uint4 r1 = *(const uint4*)&hb[(size_t)s1 * F + cl * 8];
        e0 = (e0 > 0.f) ? e0 : 0.2f * e0;
        e1 = (e1 > 0.f) ? e1 : 0.2f * e1;
        float p0 = __expf(e0);
        float p1 = __expf(e1);
        den += p0 + p1;
        acc[0] += p0 * bflo(r0.x); acc[1] += p0 * bfhi(r0.x);
        acc[2] += p0 * bflo(r0.y); acc[3] += p0 * bfhi(r0.y);
        acc[4] += p0 * bflo(r0.z); acc[5] += p0 * bfhi(r0.z);
        acc[6] += p0 * bflo(r0.w); acc[7] += p0 * bfhi(r0.w);
        acc[0] += p1 * bflo(r1.x); acc[1] += p1 * bfhi(r1.x);
        acc[2] += p1 * bflo(r1.y); acc[3] += p1 * bfhi(r1.y);
        acc[4] += p1 * bflo(r1.z); acc[5] += p1 * bfhi(r1.z);
        acc[6] += p1 * bflo(r1.w); acc[7] += p1 * bfhi(r1.w);
    }
    if (j < je) {
        int s = csr_src[j];
        float e = als[s * HEADS + head] + aldv;
        uint4 raw = *(const uint4*)&hb[(size_t)s * F + cl * 8];
        e = (e > 0.f) ? e : 0.2f * e;
        float p = __expf(e);
        den += p;
        acc[0] += p * bflo(raw.x); acc[1] += p * bfhi(raw.x);
        acc[2] += p * bflo(raw.y); acc[3] += p * bfhi(raw.y);
        acc[4] += p * bflo(raw.z); acc[5] += p * bfhi(raw.z);
        acc[6] += p * bflo(raw.w); acc[7] += p * bfhi(raw.w);
    }

#pragma unroll
    for (int i = 0; i < 8; i++) {
        acc[i] += __shfl_xor(acc[i], 16);
        acc[i] += __shfl_xor(acc[i], 32);
    }
    den += __shfl_xor(den, 16);
    den += __shfl_xor(den, 32);

    if (g == 0) {
        float inv = 1.f / den;
        float v[8];
#pragma unroll
        for (int i = 0; i < 8; i++) {
            v[i] = acc[i] * inv + bias[cl * 8 + i];
            if (apply_elu) v[i] = (v[i] > 0.f) ? v[i] : (__expf(v[i]) - 1.f);
        }
        float4* op = (float4*)&out[(size_t)n * F + cl * 8];
        op[0] = make_float4(v[0], v[1], v[2], v[3]);
        op[1] = make_float4(v[4], v[5], v[6], v[7]);
    }
}

// ---------------- launch ----------------

extern "C" void kernel_launch(void* const* d_in, const int* in_sizes, int n_in,
                              void* d_out, int out_size, void* d_ws, size_t ws_size,
                              hipStream_t stream) {
    const float* x   = (const float*)d_in[0];
    const int*   ei  = (const int*)d_in[1];
    const float* W1  = (const float*)d_in[2];
    const float* as1 = (const float*)d_in[3];
    const float* ad1 = (const float*)d_in[4];
    const float* b1  = (const float*)d_in[5];
    const float* W2  = (const float*)d_in[6];
    const float* as2 = (const float*)d_in[7];
    const float* ad2 = (const float*)d_in[8];
    const float* b2  = (const float*)d_in[9];
    float* out = (float*)d_out;

    char* ws = (char*)d_ws;
    size_t off = 0;
    auto alloc = [&](size_t bytes) {
        void* p = ws + off;
        off += (bytes + 255) & ~(size_t)255;
        return p;
    };
    unsigned short* hb = (unsigned short*)alloc((size_t)NN * F * 2);   // 12.8 MB
    float* als     = (float*)alloc((size_t)NN * HEADS * 4);
    float* ald     = (float*)alloc((size_t)NN * HEADS * 4);
    int*   counts  = (int*)alloc((size_t)NN * 4);
    int*   row_ptr = (int*)alloc((size_t)(NN + 1) * 4);
    int*   bsum    = (int*)alloc((size_t)NB * 4);
    int*   csr_src = (int*)alloc((size_t)ETOT * 4);       // 3.4 MB
    unsigned short* wf = (unsigned short*)alloc((size_t)4 * 2048 * 8 * 2);  // 128 KB

    int GG = (NN + MT - 1) / MT;           // 782 GEMM blocks
    int CG = (ETOT + 255) / 256;           // 3321 count blocks
    int agg_grid = (NN + 3) / 4;

    (void)hipMemsetAsync(counts, 0, (size_t)NN * 4, stream);
    wpack_k<<<16, 256, 0, stream>>>(W1, W2, wf);

    // ---- layer 1 GEMM (MFMA, LDS-staged W) + logits, degree-count overlapped ----
    gemm_mfma<<<GG + CG, 256, 0, stream>>>(x, wf, as1, ad1, hb, als, ald, NN,
                                           ei, counts, GG);
    scan_block_k<<<NB, 1024, 0, stream>>>(counts, row_ptr, bsum, NN);
    scan_add_k<<<(NN + 255) / 256, 256, 0, stream>>>(row_ptr, bsum, NN);
    fill_k<<<CG, 256, 0, stream>>>(ei, row_ptr, counts, csr_src);
    aggregate<<<agg_grid, 256, 0, stream>>>(hb, als, ald, row_ptr, csr_src, b1, out, 1);

    // ---- layer 2 ----
    gemm_mfma<<<GG, 256, 0, stream>>>(out, wf + (size_t)2 * 2048 * 8, as2, ad2, hb, als, ald, NN,
                                      (const int*)nullptr, (int*)nullptr, GG);
    aggregate<<<agg_grid, 256, 0, stream>>>(hb, als, ald, row_ptr, csr_src, b2, out, 0);
}

// Round 9
// 267.292 us; speedup vs baseline: 2.0785x; 1.1110x over previous
//
#include <hip/hip_runtime.h>
#include <hip/hip_bf16.h>

#define NN 50000
#define EE 800000
#define ETOT (EE + NN)
#define F 128
#define HEADS 4
#define MT 64
#define NB ((NN + 1023) / 1024)   // 49 scan chunks

typedef __bf16 bf16x8 __attribute__((ext_vector_type(8)));
typedef float  f32x4  __attribute__((ext_vector_type(4)));

// f32 -> bf16 bits, round-to-nearest-even
__device__ __forceinline__ unsigned short f32_to_bf16(float f) {
    unsigned int u = __float_as_uint(f);
    u += 0x7fffu + ((u >> 16) & 1u);
    return (unsigned short)(u >> 16);
}
__device__ __forceinline__ float bf16bits_to_f32(unsigned short s) {
    return __uint_as_float(((unsigned int)s) << 16);
}
__device__ __forceinline__ float bflo(unsigned int u) { return __uint_as_float(u << 16); }
__device__ __forceinline__ float bfhi(unsigned int u) { return __uint_as_float(u & 0xffff0000u); }

union BU { unsigned short u[8]; bf16x8 v; };

// ---------------- W pre-pack into MFMA B-fragment order, split hi/lo ----------------
// per layer: 64 KB contiguous [hi 32KB | lo 32KB]
// B-frag: lane holds B[k = kt*32 + (lane>>4)*8 + j][n = nt*16 + (lane&15)]

__global__ void wpack_k(const float* __restrict__ W1, const float* __restrict__ W2,
                        unsigned short* __restrict__ wf) {
    int t = blockIdx.x * blockDim.x + threadIdx.x;
    if (t >= 2 * 2048) return;
    int which = t >> 11;
    int rem = t & 2047;
    int lane = rem & 63;
    int tile = rem >> 6;          // kt*8+nt
    int kt = tile >> 3, nt = tile & 7;
    int q = lane >> 4, c = lane & 15;
    const float* W = which ? W2 : W1;
    BU vh, vl;
#pragma unroll
    for (int j = 0; j < 8; j++) {
        float w = W[(kt * 32 + q * 8 + j) * F + nt * 16 + c];
        unsigned short hb = f32_to_bf16(w);
        vh.u[j] = hb;
        vl.u[j] = f32_to_bf16(w - bf16bits_to_f32(hb));
    }
    size_t base_h = ((size_t)(which * 2 + 0) * 2048 + tile * 64 + lane) * 8;
    size_t base_l = ((size_t)(which * 2 + 1) * 2048 + tile * 64 + lane) * 8;
    *(bf16x8*)&wf[base_h] = vh.v;
    *(bf16x8*)&wf[base_l] = vl.v;
}

// ---------------- MFMA GEMM, W staged in LDS; layer-1: count tail fused ----------------

__launch_bounds__(256)
__global__ void gemm_mfma(const float* __restrict__ A, const unsigned short* __restrict__ wf,
                          const float* __restrict__ a_src, const float* __restrict__ a_dst,
                          unsigned short* __restrict__ Cb, float* __restrict__ als,
                          float* __restrict__ ald, int M,
                          const int* __restrict__ ei, int* __restrict__ counts,
                          int* __restrict__ pos, int gemm_blocks) {
    __shared__ unsigned char smem[65536];     // W hi+lo; epilogue aliases it
    int tid = threadIdx.x;
    int w = tid >> 6, lane = tid & 63;
    int m = lane & 15, q = lane >> 4;
    int row0 = blockIdx.x * MT + w * 16;

    // stage 64 KB of packed W into LDS (coalesced 16B per lane)
    {
        const uint4* src = (const uint4*)wf;
        uint4* dst = (uint4*)smem;
#pragma unroll
        for (int i = 0; i < 16; i++) dst[tid + i * 256] = src[tid + i * 256];
    }
    __syncthreads();

    int ar = row0 + m; if (ar >= M) ar = 0;          // clamp; stores guarded
    const float* arow = A + (size_t)ar * F + q * 8;
    const unsigned short* lds_h = (const unsigned short*)smem;            // hi
    const unsigned short* lds_l = (const unsigned short*)(smem + 32768);  // lo

    f32x4 acc[8];
#pragma unroll
    for (int nt = 0; nt < 8; nt++) acc[nt] = (f32x4){0.f, 0.f, 0.f, 0.f};

#pragma unroll
    for (int kt = 0; kt < 4; kt++) {
        float4 a0 = *(const float4*)(arow + kt * 32);
        float4 a1 = *(const float4*)(arow + kt * 32 + 4);
        float av[8] = {a0.x, a0.y, a0.z, a0.w, a1.x, a1.y, a1.z, a1.w};
        BU ah, al;
#pragma unroll
        for (int j = 0; j < 8; j++) {
            unsigned short hb = f32_to_bf16(av[j]);
            ah.u[j] = hb;
            al.u[j] = f32_to_bf16(av[j] - bf16bits_to_f32(hb));
        }
#pragma unroll
        for (int nt = 0; nt < 8; nt++) {
            int bo = ((kt * 8 + nt) * 64 + lane) * 8;
            bf16x8 bh = *(const bf16x8*)&lds_h[bo];
            bf16x8 bl = *(const bf16x8*)&lds_l[bo];
            acc[nt] = __builtin_amdgcn_mfma_f32_16x16x32_bf16(ah.v, bh, acc[nt], 0, 0, 0);
            acc[nt] = __builtin_amdgcn_mfma_f32_16x16x32_bf16(al.v, bh, acc[nt], 0, 0, 0);
            acc[nt] = __builtin_amdgcn_mfma_f32_16x16x32_bf16(ah.v, bl, acc[nt], 0, 0, 0);
        }
    }
    __syncthreads();   // all waves done reading W from LDS; safe to reuse as epilogue buffer

    // C/D layout: col = lane&15, row = q*4+reg  ->  LDS transpose (pad 132)
    float* L = (float*)smem + w * (16 * 132);
#pragma unroll
    for (int nt = 0; nt < 8; nt++)
#pragma unroll
        for (int r = 0; r < 4; r++)
            L[(q * 4 + r) * 132 + nt * 16 + m] = acc[nt][r];
    // within-wave RAW on LDS: compiler inserts lgkmcnt wait

    int rr = lane >> 2;            // row within wave tile
    int head = lane & 3;
    int c0 = head * 32;            // this lane owns head's 32 channels of row rr
    int gr = row0 + rr;
    float v[32];
#pragma unroll
    for (int i = 0; i < 8; i++)
        *(float4*)&v[i * 4] = *(const float4*)&L[rr * 132 + c0 + i * 4];

    if (gr < M) {
#pragma unroll
        for (int i = 0; i < 4; i++) {
            uint4 pk;
            pk.x = (unsigned)f32_to_bf16(v[i * 8 + 0]) | ((unsigned)f32_to_bf16(v[i * 8 + 1]) << 16);
            pk.y = (unsigned)f32_to_bf16(v[i * 8 + 2]) | ((unsigned)f32_to_bf16(v[i * 8 + 3]) << 16);
            pk.z = (unsigned)f32_to_bf16(v[i * 8 + 4]) | ((unsigned)f32_to_bf16(v[i * 8 + 5]) << 16);
            pk.w = (unsigned)f32_to_bf16(v[i * 8 + 6]) | ((unsigned)f32_to_bf16(v[i * 8 + 7]) << 16);
            *(uint4*)&Cb[(size_t)gr * F + c0 + i * 8] = pk;
        }
        float ps = 0.f, pd = 0.f;
#pragma unroll
        for (int i = 0; i < 32; i++) {
            ps += v[i] * a_src[c0 + i];
            pd += v[i] * a_dst[c0 + i];
        }
        als[gr * HEADS + head] = ps;
        ald[gr * HEADS + head] = pd;
    }

    // ---- layer-1 only: degree count + per-edge bucket offset (grid-stride tail) ----
    if (ei) {
        int stride = gemm_blocks * 256;
        for (int e = blockIdx.x * 256 + tid; e < ETOT; e += stride) {
            int dst = (e < EE) ? ei[EE + e] : (e - EE);
            pos[e] = atomicAdd(&counts[dst], 1);
        }
    }
}

// ---------------- CSR scan kernels ----------------

__launch_bounds__(1024)
__global__ void scan_block_k(const int* __restrict__ counts, int* __restrict__ row_ptr,
                             int* __restrict__ bsum, int n) {
    int tid = threadIdx.x;
    int i = blockIdx.x * 1024 + tid;
    int v = (i < n) ? counts[i] : 0;
    int lane = tid & 63;
    int wave = tid >> 6;
    int x = v;
#pragma unroll
    for (int off = 1; off < 64; off <<= 1) {
        int t = __shfl_up(x, off, 64);
        if (lane >= off) x += t;
    }
    __shared__ int wsum[16];
    if (lane == 63) wsum[wave] = x;
    __syncthreads();
    if (wave == 0) {
        int w = (lane < 16) ? wsum[lane] : 0;
#pragma unroll
        for (int off = 1; off < 16; off <<= 1) {
            int t = __shfl_up(w, off, 64);
            if (lane >= off) w += t;
        }
        if (lane < 16) wsum[lane] = w;
    }
    __syncthreads();
    int base = (wave > 0) ? wsum[wave - 1] : 0;
    int incl = base + x;
    if (i < n) row_ptr[i] = incl - v;
    if (tid == 1023) bsum[blockIdx.x] = incl;
}

__launch_bounds__(256)
__global__ void scan_add_k(int* __restrict__ row_ptr, const int* __restrict__ bsum, int n) {
    __shared__ int off_s[NB];
    if (threadIdx.x < 64) {
        int lane = threadIdx.x;
        int v = (lane < NB) ? bsum[lane] : 0;
        int x = v;
#pragma unroll
        for (int o = 1; o < 64; o <<= 1) {
            int t = __shfl_up(x, o, 64);
            if (lane >= o) x += t;
        }
        if (lane < NB) off_s[lane] = x - v;
    }
    __syncthreads();
    int i = blockIdx.x * blockDim.x + threadIdx.x;
    if (i < n) row_ptr[i] += off_s[i >> 10];
    if (i == 0) row_ptr[n] = ETOT;
}

// fill: atomic-free (uses per-edge bucket offsets recorded during counting)
__global__ void fill_k(const int* __restrict__ ei, const int* __restrict__ row_ptr,
                       const int* __restrict__ pos, int* __restrict__ csr_src) {
    int e = blockIdx.x * blockDim.x + threadIdx.x;
    if (e >= ETOT) return;
    int src, dst;
    if (e < EE) { src = ei[e]; dst = ei[EE + e]; }
    else        { src = e - EE; dst = e - EE; }
    csr_src[row_ptr[dst] + pos[e]] = src;
}

// ---------------- softmax + aggregate: wave/node, 4 groups x 16 lanes, 2-edge ILP ----

__launch_bounds__(256)
__global__ void aggregate(const unsigned short* __restrict__ hb, const float* __restrict__ als,
                          const float* __restrict__ ald, const int* __restrict__ row_ptr,
                          const int* __restrict__ csr_src, const float* __restrict__ bias,
                          float* __restrict__ out, int apply_elu) {
    int wave = threadIdx.x >> 6;
    int n = blockIdx.x * 4 + wave;
    if (n >= NN) return;
    int lane = threadIdx.x & 63;
    int g  = lane >> 4;
    int cl = lane & 15;
    int head = cl >> 2;
    float aldv = ald[n * HEADS + head];
    int jb = row_ptr[n], je = row_ptr[n + 1];

    float acc[8];
#pragma unroll
    for (int i = 0; i < 8; i++) acc[i] = 0.f;
    float den = 0.f;

    int j = jb + g;
    for (; j + 4 < je; j += 8) {
        int s0 = csr_src[j];
        int s1 = csr_src[j + 4];
        float e0 = als[s0 * HEADS + head] + aldv;
        float e1 = als[s1 * HEADS + head] + aldv;
        uint4 r0 = *(const uint4*)&hb[(size_t)s0 * F + cl * 8];
        uint4 r1 = *(const uint4*)&hb[(size_t)s1 * F + cl * 8];
        e0 = (e0 > 0.f) ? e0 : 0.2f * e0;
        e1 = (e1 > 0.f) ? e1 : 0.2f * e1;
        float p0 = __expf(e0);
        float p1 = __expf(e1);
        den += p0 + p1;
        acc[0] += p0 * bflo(r0.x); acc[1] += p0 * bfhi(r0.x);
        acc[2] += p0 * bflo(r0.y); acc[3] += p0 * bfhi(r0.y);
        acc[4] += p0 * bflo(r0.z); acc[5] += p0 * bfhi(r0.z);
        acc[6] += p0 * bflo(r0.w); acc[7] += p0 * bfhi(r0.w);
        acc[0] += p1 * bflo(r1.x); acc[1] += p1 * bfhi(r1.x);
        acc[2] += p1 * bflo(r1.y); acc[3] += p1 * bfhi(r1.y);
        acc[4] += p1 * bflo(r1.z); acc[5] += p1 * bfhi(r1.z);
        acc[6] += p1 * bflo(r1.w); acc[7] += p1 * bfhi(r1.w);
    }
    if (j < je) {
        int s = csr_src[j];
        float e = als[s * HEADS + head] + aldv;
        uint4 raw = *(const uint4*)&hb[(size_t)s * F + cl * 8];
        e = (e > 0.f) ? e : 0.2f * e;
        float p = __expf(e);
        den += p;
        acc[0] += p * bflo(raw.x); acc[1] += p * bfhi(raw.x);
        acc[2] += p * bflo(raw.y); acc[3] += p * bfhi(raw.y);
        acc[4] += p * bflo(raw.z); acc[5] += p * bfhi(raw.z);
        acc[6] += p * bflo(raw.w); acc[7] += p * bfhi(raw.w);
    }

#pragma unroll
    for (int i = 0; i < 8; i++) {
        acc[i] += __shfl_xor(acc[i], 16);
        acc[i] += __shfl_xor(acc[i], 32);
    }
    den += __shfl_xor(den, 16);
    den += __shfl_xor(den, 32);

    if (g == 0) {
        float inv = 1.f / den;
        float v[8];
#pragma unroll
        for (int i = 0; i < 8; i++) {
            v[i] = acc[i] * inv + bias[cl * 8 + i];
            if (apply_elu) v[i] = (v[i] > 0.f) ? v[i] : (__expf(v[i]) - 1.f);
        }
        float4* op = (float4*)&out[(size_t)n * F + cl * 8];
        op[0] = make_float4(v[0], v[1], v[2], v[3]);
        op[1] = make_float4(v[4], v[5], v[6], v[7]);
    }
}

// ---------------- launch ----------------

extern "C" void kernel_launch(void* const* d_in, const int* in_sizes, int n_in,
                              void* d_out, int out_size, void* d_ws, size_t ws_size,
                              hipStream_t stream) {
    const float* x   = (const float*)d_in[0];
    const int*   ei  = (const int*)d_in[1];
    const float* W1  = (const float*)d_in[2];
    const float* as1 = (const float*)d_in[3];
    const float* ad1 = (const float*)d_in[4];
    const float* b1  = (const float*)d_in[5];
    const float* W2  = (const float*)d_in[6];
    const float* as2 = (const float*)d_in[7];
    const float* ad2 = (const float*)d_in[8];
    const float* b2  = (const float*)d_in[9];
    float* out = (float*)d_out;

    char* ws = (char*)d_ws;
    size_t off = 0;
    auto alloc = [&](size_t bytes) {
        void* p = ws + off;
        off += (bytes + 255) & ~(size_t)255;
        return p;
    };
    unsigned short* hb = (unsigned short*)alloc((size_t)NN * F * 2);   // 12.8 MB
    float* als     = (float*)alloc((size_t)NN * HEADS * 4);
    float* ald     = (float*)alloc((size_t)NN * HEADS * 4);
    int*   counts  = (int*)alloc((size_t)NN * 4);
    int*   row_ptr = (int*)alloc((size_t)(NN + 1) * 4);
    int*   bsum    = (int*)alloc((size_t)NB * 4);
    int*   csr_src = (int*)alloc((size_t)ETOT * 4);       // 3.4 MB
    int*   pos     = (int*)alloc((size_t)ETOT * 4);       // 3.4 MB
    unsigned short* wf = (unsigned short*)alloc((size_t)4 * 2048 * 8 * 2);  // 128 KB

    int GG = (NN + MT - 1) / MT;           // 782 GEMM blocks
    int agg_grid = (NN + 3) / 4;

    (void)hipMemsetAsync(counts, 0, (size_t)NN * 4, stream);
    wpack_k<<<16, 256, 0, stream>>>(W1, W2, wf);

    // ---- layer 1 GEMM (MFMA, LDS-staged W) + logits, count tail fused ----
    gemm_mfma<<<GG, 256, 0, stream>>>(x, wf, as1, ad1, hb, als, ald, NN,
                                      ei, counts, pos, GG);
    scan_block_k<<<NB, 1024, 0, stream>>>(counts, row_ptr, bsum, NN);
    scan_add_k<<<(NN + 255) / 256, 256, 0, stream>>>(row_ptr, bsum, NN);
    fill_k<<<(ETOT + 255) / 256, 256, 0, stream>>>(ei, row_ptr, pos, csr_src);
    aggregate<<<agg_grid, 256, 0, stream>>>(hb, als, ald, row_ptr, csr_src, b1, out, 1);

    // ---- layer 2 ----
    gemm_mfma<<<GG, 256, 0, stream>>>(out, wf + (size_t)2 * 2048 * 8, as2, ad2, hb, als, ald, NN,
                                      (const int*)nullptr, (int*)nullptr, (int*)nullptr, GG);
    aggregate<<<agg_grid, 256, 0, stream>>>(hb, als, ald, row_ptr, csr_src, b2, out, 0);
}